// Round 12
// baseline (904.223 us; speedup 1.0000x reference)
//
#include <hip/hip_runtime.h>
#include <hip/hip_bf16.h>

// Problem constants
#define BN 2048
#define MN 64
#define DN 256
#define EMB_ROWS 50001
#define EMB_PAD 50016
#define LN_EPS 1e-5f
#define SPLITK 16
#define KCHUNK 4096   // 65536 / SPLITK

typedef __hip_bfloat16 bf16;
typedef __attribute__((ext_vector_type(8))) short bf16x8;
typedef __attribute__((ext_vector_type(4))) float f32x4;

static __device__ __forceinline__ short f2bf(float f) {
  return __builtin_bit_cast(short, __float2bfloat16(f));
}
static __device__ __forceinline__ float bfu(unsigned short u) {
  unsigned int x = ((unsigned int)u) << 16;
  return __builtin_bit_cast(float, x);
}
// fast sigmoid via v_exp_f32
static __device__ __forceinline__ float fsig(float x) {
  return 1.f / (1.f + __expf(-x));
}

typedef __attribute__((address_space(1))) const void g_void;
typedef __attribute__((address_space(3))) void l_void;
static __device__ __forceinline__ void gl_lds16(const void* g, void* l) {
  __builtin_amdgcn_global_load_lds((g_void*)g, (l_void*)l, 16, 0, 0);
}

// ---- device helpers for the batched precompute ----
static __device__ __forceinline__ void dev_mm(float* __restrict__ C, const float* __restrict__ A,
                                              const float* __restrict__ B, int N, int K,
                                              int aI, int aM, int bM, int bJ, int blk, int tid) {
  int idx = blk * 256 + tid;
  int i = idx / N, j = idx - i * N;
  float s = 0.f;
  for (int m = 0; m < K; ++m) s += A[i * aI + m * aM] * B[m * bM + j * bJ];
  C[idx] = s;
}
static __device__ __forceinline__ void dev_tr(float* __restrict__ dst, const float* __restrict__ src,
                                              int rows, int cols, int blk, int tid) {
  int idx = blk * 256 + tid;
  int r = idx / cols, c = idx - r * cols;
  dst[c * rows + r] = src[idx];
}

// ================= stage 1: all independent precompute in ONE launch =================
#define S1_GRID 27349
__global__ void k_stage1(const float* __restrict__ Wbil_t, const float* __restrict__ Wq_t,
                         const float* __restrict__ Wbil_e, const float* __restrict__ Wq_e,
                         const float* __restrict__ Wo_t, const float* __restrict__ Wv_t,
                         const float* __restrict__ Wo_e, const float* __restrict__ Wv_e,
                         const float* __restrict__ Wtail, const float* __restrict__ Whead,
                         const float* __restrict__ W1, const float* __restrict__ W2,
                         const float* __restrict__ Wg, const float* __restrict__ Ug,
                         const float* __restrict__ Wr, const float* __restrict__ Ur,
                         const float* __restrict__ Wrel, const float* __restrict__ emb,
                         const int* __restrict__ pairs,
                         float* __restrict__ T_t, float* __restrict__ T_e,
                         float* __restrict__ Wov_t, float* __restrict__ Wov_e,
                         float* __restrict__ WtailT, float* __restrict__ Whead_kn,
                         float* __restrict__ W1_kn, float* __restrict__ W2_kn,
                         bf16* __restrict__ wcat, bf16* __restrict__ emb_bf,
                         float* __restrict__ eL, float* __restrict__ eR,
                         bf16* __restrict__ eRbf, float* __restrict__ eLT,
                         bf16* __restrict__ Wrel_bf) {
  int bid = blockIdx.x, tid = threadIdx.x;
  if (bid < 256)        dev_mm(T_t, Wbil_t, Wq_t, 256, 256, 256, 1, 256, 1, bid, tid);
  else if (bid < 512)   dev_mm(T_e, Wbil_e, Wq_e, 256, 256, 256, 1, 256, 1, bid - 256, tid);
  else if (bid < 768)   dev_mm(Wov_t, Wo_t, Wv_t, 256, 256, 256, 1, 256, 1, bid - 512, tid);
  else if (bid < 1024)  dev_mm(Wov_e, Wo_e, Wv_e, 256, 256, 256, 1, 256, 1, bid - 768, tid);
  else if (bid < 1280)  dev_tr(WtailT, Wtail, 256, 256, bid - 1024, tid);
  else if (bid < 1536)  dev_tr(Whead_kn, Whead, 256, 256, bid - 1280, tid);
  else if (bid < 2560)  dev_tr(W1_kn, W1, 512, 512, bid - 1536, tid);
  else if (bid < 3584)  dev_tr(W2_kn, W2, 512, 512, bid - 2560, tid);
  else if (bid < 4608) {            // wcat bf16 [n][k] = W[k][n] for [Wg|Ug|Wr|Ur]
    int idx = (bid - 3584) * 256 + tid;
    int n = idx >> 8, k = idx & 255;
    const float* s = (n < 256) ? Wg : (n < 512) ? Ug : (n < 768) ? Wr : Ur;
    wcat[idx] = __float2bfloat16(s[k * 256 + (n & 255)]);
  } else if (bid < 17109) {         // emb f32 -> bf16
    int i = (bid - 4608) * 256 + tid;
    if (i < (EMB_ROWS * 256) / 4) {
      float4 v = ((const float4*)emb)[i];
      ushort4 o;
      o.x = (unsigned short)f2bf(v.x); o.y = (unsigned short)f2bf(v.y);
      o.z = (unsigned short)f2bf(v.z); o.w = (unsigned short)f2bf(v.w);
      ((ushort4*)emb_bf)[i] = o;
    }
  } else if (bid < 19157) {         // gather eL/eR (+bf16 eR, transposed eL)
    int b = bid - 17109, d = tid;
    float vL = emb[(size_t)pairs[2 * b] * 256 + d];
    float vR = emb[(size_t)pairs[2 * b + 1] * 256 + d];
    eL[b * 256 + d] = vL;
    eR[b * 256 + d] = vR;
    eRbf[b * 256 + d] = __float2bfloat16(vR);
    eLT[(size_t)d * BN + b] = vL;
  } else {                          // Wrel f32 -> bf16
    int blk = bid - 19157;
    int base = blk * 1024 + tid;
    #pragma unroll
    for (int it = 0; it < 4; ++it) {
      int i = base + it * 256;
      float4 v = ((const float4*)Wrel)[i];
      ushort4 o;
      o.x = (unsigned short)f2bf(v.x); o.y = (unsigned short)f2bf(v.y);
      o.z = (unsigned short)f2bf(v.z); o.w = (unsigned short)f2bf(v.w);
      ((ushort4*)Wrel_bf)[i] = o;
    }
  }
}

// ================= bilinear: PROVEN 2-phase double-buffer; now 3 blocks/CU for drain overlap ===
// Lockstep drain rate-matches the 16 bx-sibling blocks per XCD so Wrel tiles stay
// L2-resident. Do NOT pipeline (R7: counted-vmcnt decoheres siblings -> 1GB FETCH, 2.3x slower).
// (256,3): third resident block fills the barrier-drain window (m114 overlap). Watch FETCH;
// if it blows past ~100MB the bigger resident set broke L2 sharing -> revert to (256,2).
__global__ __launch_bounds__(256, 3) void k_bilinear(const bf16* __restrict__ eRbf,
                                                     const float* __restrict__ eLT,
                                                     const bf16* __restrict__ wrel,
                                                     float* __restrict__ part) {
  __shared__ char bsh[2][8192];   // 2 x (64 rows x 64 bf16)
  int bid = blockIdx.x;
  int lid = (bid & 7) * 256 + (bid >> 3);   // bijective XCD swizzle (2048 % 8 == 0)
  int bx = lid & 15, by = (lid >> 4) & 7, bz = lid >> 7;
  int tid = threadIdx.x, w = tid >> 6, lane = tid & 63;
  int l16 = lane & 15, lq = lane >> 4;
  int kfo = lq * 8;
  int m_base = bx * 128 + w * 32;
  int n0 = by * 64;
  int i0 = bz * 16;

  bf16x8 ar[2][8];
  #pragma unroll
  for (int mi = 0; mi < 2; ++mi) {
    const bf16* er = eRbf + (size_t)(m_base + mi * 16 + l16) * 256 + kfo;
    #pragma unroll
    for (int jb = 0; jb < 8; ++jb) ar[mi][jb] = *(const bf16x8*)(er + jb * 32);
  }

  f32x4 z = {0.f, 0.f, 0.f, 0.f};
  f32x4 accF[2][4];
  f32x4 P[2][4];
  #pragma unroll
  for (int mi = 0; mi < 2; ++mi)
    #pragma unroll
    for (int nf = 0; nf < 4; ++nf) { accF[mi][nf] = z; P[mi][nf] = z; }

  int srow = tid >> 3, sblk = tid & 7;
  const bf16* wbase = wrel + (size_t)n0 * 65536 + (size_t)i0 * 256;
  auto stage = [&](int c, int step) {
    size_t so = (size_t)step * 64;
    #pragma unroll
    for (int q = 0; q < 2; ++q) {
      int r = q * 32 + srow;
      const bf16* src = wbase + (size_t)r * 65536 + so + (size_t)((sblk ^ (r & 7)) << 3);
      gl_lds16(src, &bsh[c][q * 4096 + w * 1024]);
    }
  };

  stage(0, 0);
  __syncthreads();
  int cur = 0;
  for (int s = 0; s < 16; ++s) {
    const float* elb = eLT + (size_t)(i0 + s) * BN + m_base + lq * 4;
    float4 el0 = *(const float4*)(elb);
    float4 el1 = *(const float4*)(elb + 16);
    #pragma unroll
    for (int jb4 = 0; jb4 < 4; ++jb4) {
      int step = s * 4 + jb4;
      if (step + 1 < 64) stage(cur ^ 1, step + 1);
      bf16x8 bq[2][4];
      #pragma unroll
      for (int kk = 0; kk < 2; ++kk)
        #pragma unroll
        for (int nf = 0; nf < 4; ++nf) {
          int rl = nf * 16 + l16;
          int blk = (kk * 4 + lq) ^ (l16 & 7);
          bq[kk][nf] = *(const bf16x8*)&bsh[cur][rl * 128 + (blk << 4)];
        }
      #pragma unroll
      for (int kk = 0; kk < 2; ++kk)
        #pragma unroll
        for (int mi = 0; mi < 2; ++mi)
          #pragma unroll
          for (int nf = 0; nf < 4; ++nf) {
            if (jb4 == 0 && kk == 0)
              P[mi][nf] = __builtin_amdgcn_mfma_f32_16x16x32_bf16(ar[mi][jb4 * 2 + kk], bq[kk][nf], z, 0, 0, 0);
            else
              P[mi][nf] = __builtin_amdgcn_mfma_f32_16x16x32_bf16(ar[mi][jb4 * 2 + kk], bq[kk][nf], P[mi][nf], 0, 0, 0);
          }
      __syncthreads();
      cur ^= 1;
    }
    #pragma unroll
    for (int mi = 0; mi < 2; ++mi) {
      float4 el = mi ? el1 : el0;
      #pragma unroll
      for (int nf = 0; nf < 4; ++nf) {
        accF[mi][nf][0] += el.x * P[mi][nf][0];
        accF[mi][nf][1] += el.y * P[mi][nf][1];
        accF[mi][nf][2] += el.z * P[mi][nf][2];
        accF[mi][nf][3] += el.w * P[mi][nf][3];
      }
    }
  }

  float* p = part + (size_t)bz * BN * 512;
  #pragma unroll
  for (int mi = 0; mi < 2; ++mi) {
    #pragma unroll
    for (int nf = 0; nf < 4; ++nf) {
      int col = n0 + nf * 16 + l16;
      #pragma unroll
      for (int r = 0; r < 4; ++r) {
        int row = m_base + mi * 16 + lq * 4 + r;
        p[(size_t)row * 512 + col] = accF[mi][nf][r];
      }
    }
  }
}

// ================= e4 body v4: quadrant LDS + coalesced epilogue (R10-proven) ====
static __device__ __forceinline__ void dev_e4(char* wsh, char* tb, int bid,
                                              const bf16* __restrict__ embbf,
                                              const bf16* __restrict__ wcat, bf16* __restrict__ E4) {
  int lid = (bid & 7) * 392 + (bid >> 3);   // bijective: 3136 = 8*392
  int mchunk = lid >> 4, nt = lid & 15;
  int tid = threadIdx.x;
  int w = tid >> 6, lane = tid & 63;
  int l16 = lane & 15, lq = lane >> 4, kfo = lq * 8;
  int n0 = nt * 64;

  #pragma unroll
  for (int issue = 0; issue < 8; ++issue) {
    int L = issue * 4096 + tid * 16;
    int q = L >> 13;
    int rl = (L >> 7) & 63;
    int blk = (L >> 4) & 7;
    const bf16* src = wcat + (size_t)(n0 + rl) * 256 + q * 64 + ((blk ^ (rl & 7)) << 3);
    gl_lds16(src, wsh + L);
  }
  __syncthreads();

  char* tw = tb + w * 2176;   // per-wave transpose buffer: 16 rows x 136B
  int trow = lane >> 2, tc = lane & 3;
  f32x4 z = {0.f, 0.f, 0.f, 0.f};
  #pragma unroll
  for (int g = 0; g < 4; ++g) {
    int rbase = mchunk * 256 + w * 64 + g * 16;
    int arow = rbase + l16; if (arow >= EMB_ROWS) arow = EMB_ROWS - 1;
    const bf16* ap = embbf + (size_t)arow * 256 + kfo;
    bf16x8 A[8];
    #pragma unroll
    for (int ks = 0; ks < 8; ++ks) A[ks] = *(const bf16x8*)(ap + ks * 32);
    f32x4 acc[4];
    #pragma unroll
    for (int nf = 0; nf < 4; ++nf) acc[nf] = z;
    #pragma unroll
    for (int ks = 0; ks < 8; ++ks) {
      int qd = ks >> 1, kk = ks & 1;
      bf16x8 bq[4];
      #pragma unroll
      for (int nf = 0; nf < 4; ++nf) {
        int rl = nf * 16 + l16;
        int blk = (kk * 4 + lq) ^ (l16 & 7);
        bq[nf] = *(const bf16x8*)&wsh[qd * 8192 + rl * 128 + (blk << 4)];
      }
      acc[0] = __builtin_amdgcn_mfma_f32_16x16x32_bf16(A[ks], bq[0], acc[0], 0, 0, 0);
      acc[1] = __builtin_amdgcn_mfma_f32_16x16x32_bf16(A[ks], bq[1], acc[1], 0, 0, 0);
      acc[2] = __builtin_amdgcn_mfma_f32_16x16x32_bf16(A[ks], bq[2], acc[2], 0, 0, 0);
      acc[3] = __builtin_amdgcn_mfma_f32_16x16x32_bf16(A[ks], bq[3], acc[3], 0, 0, 0);
    }
    #pragma unroll
    for (int nf = 0; nf < 4; ++nf)
      #pragma unroll
      for (int r = 0; r < 4; ++r)
        *(bf16*)(tw + (lq * 4 + r) * 136 + (nf * 16 + l16) * 2) = __float2bfloat16(acc[nf][r]);
    int orow = rbase + trow;
    #pragma unroll
    for (int it = 0; it < 2; ++it) {
      bf16x8 vv = *(const bf16x8*)(tw + trow * 136 + (tc + 4 * it) * 16);
      if (orow < EMB_ROWS)
        *(bf16x8*)(E4 + (size_t)orow * 1024 + n0 + (tc + 4 * it) * 8) = vv;
    }
  }
}

// ================= e4 + stage2 weight products =================
__global__ __launch_bounds__(256, 2) void k_e4s2(const bf16* __restrict__ embbf, const bf16* __restrict__ wcat,
                                                 bf16* __restrict__ E4,
                                                 const float* __restrict__ T_t, const float* __restrict__ Wk_t,
                                                 float* __restrict__ Cq_t,
                                                 const float* __restrict__ T_e, const float* __restrict__ Wk_e,
                                                 float* __restrict__ Cq_e,
                                                 const float* __restrict__ Wov_t, const float* __restrict__ WtailT,
                                                 float* __restrict__ Wenh_t,
                                                 const float* __restrict__ Wov_e, float* __restrict__ Wenh_e,
                                                 const float* __restrict__ Wtail, const float* __restrict__ bo_t,
                                                 const float* __restrict__ bo_e,
                                                 float* __restrict__ benh_t, float* __restrict__ benh_e) {
  __shared__ char wsh[32768 + 4 * 2176];
  int bid = blockIdx.x, tid = threadIdx.x;
  if (bid < 3136) {
    dev_e4(wsh, wsh + 32768, bid, embbf, wcat, E4);
    return;
  }
  int b2 = bid - 3136;
  if (b2 < 256)       dev_mm(Cq_t, T_t, Wk_t, 256, 256, 1, 256, 256, 1, b2, tid);
  else if (b2 < 512)  dev_mm(Cq_e, T_e, Wk_e, 256, 256, 1, 256, 256, 1, b2 - 256, tid);
  else if (b2 < 768)  dev_mm(Wenh_t, Wov_t, WtailT, 256, 256, 1, 256, 256, 1, b2 - 512, tid);
  else if (b2 < 1024) dev_mm(Wenh_e, Wov_e, WtailT, 256, 256, 1, 256, 256, 1, b2 - 768, tid);
  else {
    float s1 = 0.f, s2 = 0.f;
    for (int m = 0; m < 256; ++m) {
      float wv = Wtail[tid * 256 + m];
      s1 += wv * bo_t[m];
      s2 += wv * bo_e[m];
    }
    benh_t[tid] = s1;
    benh_e[tid] = s2;
  }
}

// ================= merged vbuild + qk12 =================
// vbuild v2: ALL gather loads issued before any math (16 outstanding VMEM/thread vs 8;
// R11 showed gather-latency-bound: VALU cut 59->45% left dur unchanged).
static __device__ __forceinline__ void dev_vbuild(int bid, const int* __restrict__ lconn,
                                                  const int* __restrict__ rconn,
                                                  const bf16* __restrict__ embbf, const bf16* __restrict__ E4,
                                                  const float* __restrict__ bg, const float* __restrict__ br,
                                                  bf16* __restrict__ Vh, bf16* __restrict__ Vt) {
  int task = bid * 4 + (threadIdx.x >> 6);
  int lane = threadIdx.x & 63;
  int d0 = lane * 4;
  // all indices first
  int i0 = lconn[2 * task], i1 = lconn[2 * task + 1];
  int r0 = rconn[2 * task], r1 = rconn[2 * task + 1];
  // all gathers issued back-to-back (independent address streams)
  ushort4 Lga = *(const ushort4*)(E4 + (size_t)i0 * 1024 + d0);
  ushort4 Lgb = *(const ushort4*)(E4 + (size_t)i1 * 1024 + 256 + d0);
  ushort4 Lea = *(const ushort4*)(embbf + (size_t)i0 * 256 + d0);
  ushort4 Leb = *(const ushort4*)(embbf + (size_t)i1 * 256 + d0);
  ushort4 Rga = *(const ushort4*)(E4 + (size_t)r0 * 1024 + 512 + d0);
  ushort4 Rgb = *(const ushort4*)(E4 + (size_t)r1 * 1024 + 768 + d0);
  ushort4 Rea = *(const ushort4*)(embbf + (size_t)r0 * 256 + d0);
  ushort4 Reb = *(const ushort4*)(embbf + (size_t)r1 * 256 + d0);
  float4 bgv = *(const float4*)(bg + d0);
  float4 brv = *(const float4*)(br + d0);
  ushort4 oh, ot;
  {
    float g = fsig(bfu(Lga.x) + bfu(Lgb.x) + bgv.x);
    oh.x = (unsigned short)f2bf(fmaxf(g * bfu(Lea.x) + (1.f - g) * bfu(Leb.x), 0.f));
    g = fsig(bfu(Lga.y) + bfu(Lgb.y) + bgv.y);
    oh.y = (unsigned short)f2bf(fmaxf(g * bfu(Lea.y) + (1.f - g) * bfu(Leb.y), 0.f));
    g = fsig(bfu(Lga.z) + bfu(Lgb.z) + bgv.z);
    oh.z = (unsigned short)f2bf(fmaxf(g * bfu(Lea.z) + (1.f - g) * bfu(Leb.z), 0.f));
    g = fsig(bfu(Lga.w) + bfu(Lgb.w) + bgv.w);
    oh.w = (unsigned short)f2bf(fmaxf(g * bfu(Lea.w) + (1.f - g) * bfu(Leb.w), 0.f));
  }
  {
    float g = fsig(bfu(Rga.x) + bfu(Rgb.x) + brv.x);
    ot.x = (unsigned short)f2bf(fmaxf(g * bfu(Rea.x) + (1.f - g) * bfu(Reb.x), 0.f));
    g = fsig(bfu(Rga.y) + bfu(Rgb.y) + brv.y);
    ot.y = (unsigned short)f2bf(fmaxf(g * bfu(Rea.y) + (1.f - g) * bfu(Reb.y), 0.f));
    g = fsig(bfu(Rga.z) + bfu(Rgb.z) + brv.z);
    ot.z = (unsigned short)f2bf(fmaxf(g * bfu(Rea.z) + (1.f - g) * bfu(Reb.z), 0.f));
    g = fsig(bfu(Rga.w) + bfu(Rgb.w) + brv.w);
    ot.w = (unsigned short)f2bf(fmaxf(g * bfu(Rea.w) + (1.f - g) * bfu(Reb.w), 0.f));
  }
  *(ushort4*)(Vh + (size_t)task * 256 + d0) = oh;
  *(ushort4*)(Vt + (size_t)task * 256 + d0) = ot;
}

__global__ __launch_bounds__(256) void k_vq(const int* __restrict__ lconn, const int* __restrict__ rconn,
                                            const bf16* __restrict__ embbf, const bf16* __restrict__ E4,
                                            const float* __restrict__ bg, const float* __restrict__ br,
                                            bf16* __restrict__ Vh, bf16* __restrict__ Vt,
                                            const float* __restrict__ part, const float* __restrict__ Cq,
                                            float* __restrict__ qkb) {
  __shared__ float xs[16][256];
  int bid = blockIdx.x, tid = threadIdx.x;
  if (bid < 32768) {
    dev_vbuild(bid, lconn, rconn, embbf, E4, bg, br, Vh, Vt);
    return;
  }
  // qk12: inline split-K reduce + Cq matmul (chains 1+2)
  int b2 = bid - 32768;
  int half = b2 >> 7;
  int r0 = (b2 & 127) * 16;
  int col0 = half * 256;
  for (int t = tid; t < 16 * 256; t += 256) {
    int r = t >> 8, k = t & 255;
    const float* pp = part + (size_t)(r0 + r) * 512 + col0 + k;
    float s = 0.f;
    #pragma unroll
    for (int zc = 0; zc < SPLITK; ++zc) s += pp[(size_t)zc * BN * 512];
    xs[r][k] = s;
  }
  __syncthreads();
  float acc[16];
  #pragma unroll
  for (int r = 0; r < 16; ++r) acc[r] = 0.f;
  for (int k4 = 0; k4 < 256; k4 += 4) {
    float w0 = Cq[(k4 + 0) * 256 + tid];
    float w1 = Cq[(k4 + 1) * 256 + tid];
    float w2 = Cq[(k4 + 2) * 256 + tid];
    float w3 = Cq[(k4 + 3) * 256 + tid];
    #pragma unroll
    for (int r = 0; r < 16; ++r) {
      float4 a = *(const float4*)&xs[r][k4];
      acc[r] += a.x * w0 + a.y * w1 + a.z * w2 + a.w * w3;
    }
  }
  int ob = half * 2048 + r0;
  #pragma unroll
  for (int r = 0; r < 16; ++r) qkb[(size_t)(ob + r) * 256 + tid] = acc[r];
}

// ================= qk stage B: two-input Cq matmul (chains 3+4) =================
__global__ __launch_bounds__(256) void k_qk34(const float* __restrict__ X0, const float* __restrict__ X1,
                                              const float* __restrict__ Cq, float* __restrict__ qkb) {
  __shared__ float xs[16][256];
  int bid = blockIdx.x, tid = threadIdx.x;
  int half = bid >> 7;
  const float* X = half ? X1 : X0;
  int r0 = (bid & 127) * 16;
  for (int t = tid; t < 16 * 256; t += 256) {
    int r = t >> 8, k = t & 255;
    xs[r][k] = X[(size_t)(r0 + r) * 256 + k];
  }
  __syncthreads();
  float acc[16];
  #pragma unroll
  for (int r = 0; r < 16; ++r) acc[r] = 0.f;
  for (int k4 = 0; k4 < 256; k4 += 4) {
    float w0 = Cq[(k4 + 0) * 256 + tid];
    float w1 = Cq[(k4 + 1) * 256 + tid];
    float w2 = Cq[(k4 + 2) * 256 + tid];
    float w3 = Cq[(k4 + 3) * 256 + tid];
    #pragma unroll
    for (int r = 0; r < 16; ++r) {
      float4 a = *(const float4*)&xs[r][k4];
      acc[r] += a.x * w0 + a.y * w1 + a.z * w2 + a.w * w3;
    }
  }
  int ob = half * 2048 + r0;
  #pragma unroll
  for (int r = 0; r < 16; ++r) qkb[(size_t)(ob + r) * 256 + tid] = acc[r];
}

// ================= dual-chain factorized attention (grid 4096) =================
__global__ __launch_bounds__(256) void k_attn_dual(const float* __restrict__ qk,
                                                   const int* __restrict__ lconn, const int* __restrict__ rconn,
                                                   const bf16* __restrict__ Vh, const bf16* __restrict__ Vt,
                                                   int sel, const bf16* __restrict__ embbf,
                                                   float* __restrict__ ov) {
  __shared__ float ss[64];
  __shared__ float as[64];
  __shared__ float ps[4][256];
  int bid = blockIdx.x;
  int b = bid & 2047;
  const int* conn = (bid < 2048) ? lconn : rconn;
  const bf16* Vbuf = (bid < 2048) ? Vh : Vt;
  int tid = threadIdx.x;
  int w = tid >> 6, lane = tid & 63;
  float4 qv = *(const float4*)(qk + (size_t)bid * 256 + lane * 4);
  for (int mi = 0; mi < 16; ++mi) {
    int m = w * 16 + mi;
    int idx = conn[((size_t)b * 64 + m) * 2 + sel];
    ushort4 kr = *(const ushort4*)(embbf + (size_t)idx * 256 + lane * 4);
    float p = qv.x * bfu(kr.x) + qv.y * bfu(kr.y) + qv.z * bfu(kr.z) + qv.w * bfu(kr.w);
    #pragma unroll
    for (int off = 32; off; off >>= 1) p += __shfl_xor(p, off, 64);
    if (lane == 0) ss[m] = p;
  }
  __syncthreads();
  if (w == 0) {
    float v = ss[lane];
    float mx = v;
    #pragma unroll
    for (int off = 32; off; off >>= 1) mx = fmaxf(mx, __shfl_xor(mx, off, 64));
    float e = __expf(v - mx);
    float sum = e;
    #pragma unroll
    for (int off = 32; off; off >>= 1) sum += __shfl_xor(sum, off, 64);
    as[lane] = e / sum;
  }
  __syncthreads();
  const bf16* vrow = Vbuf + (size_t)b * 64 * 256;
  float4 a4 = {0.f, 0.f, 0.f, 0.f};
  for (int mi = 0; mi < 16; ++mi) {
    int m = w * 16 + mi;
    float sc = as[m];
    ushort4 v4 = *(const ushort4*)(vrow + (size_t)m * 256 + lane * 4);
    a4.x += sc * bfu(v4.x);
    a4.y += sc * bfu(v4.y);
    a4.z += sc * bfu(v4.z);
    a4.w += sc * bfu(v4.w);
  }
  *(float4*)&ps[w][lane * 4] = a4;
  __syncthreads();
  float o = ps[0][tid] + ps[1][tid] + ps[2][tid] + ps[3][tid];
  ov[(size_t)bid * 256 + tid] = o;
}

// ================= dual-chain fused enhance (grid 256) =================
__global__ __launch_bounds__(256) void k_enh_dual(const float* __restrict__ ovb,
                                                  const float* __restrict__ e0, const float* __restrict__ e1,
                                                  const float* __restrict__ Wenh_kn, const float* __restrict__ Whead_kn,
                                                  const float* __restrict__ benh, const float* __restrict__ lng,
                                                  const float* __restrict__ lnb,
                                                  float* __restrict__ out0, float* __restrict__ out1,
                                                  int ostride, int ob0, int ob1) {
  __shared__ float x1[16][256];
  __shared__ float x2[16][256];
  __shared__ float stats[16][2];
  int bid = blockIdx.x, tid = threadIdx.x;
  int half = bid >> 7;
  const float* e = half ? e1 : e0;
  float* outp = half ? out1 : out0;
  int obase = half ? ob1 : ob0;
  int r0 = (bid & 127) * 16;
  int ovr0 = half * 2048 + r0;
  for (int t = tid; t < 16 * 256; t += 256) {
    int r = t >> 8, k = t & 255;
    x1[r][k] = ovb[(size_t)(ovr0 + r) * 256 + k];
    x2[r][k] = e[(size_t)(r0 + r) * 256 + k];
  }
  __syncthreads();
  float acc[16];
  #pragma unroll
  for (int r = 0; r < 16; ++r) acc[r] = 0.f;
  for (int k4 = 0; k4 < 256; k4 += 4) {
    float w10 = Wenh_kn[(k4 + 0) * 256 + tid], w11 = Wenh_kn[(k4 + 1) * 256 + tid];
    float w12 = Wenh_kn[(k4 + 2) * 256 + tid], w13 = Wenh_kn[(k4 + 3) * 256 + tid];
    float w20 = Whead_kn[(k4 + 0) * 256 + tid], w21 = Whead_kn[(k4 + 1) * 256 + tid];
    float w22 = Whead_kn[(k4 + 2) * 256 + tid], w23 = Whead_kn[(k4 + 3) * 256 + tid];
    #pragma unroll
    for (int r = 0; r < 16; ++r) {
      float4 a = *(const float4*)&x1[r][k4];
      float4 bb = *(const float4*)&x2[r][k4];
      acc[r] += a.x * w10 + a.y * w11 + a.z * w12 + a.w * w13
              + bb.x * w20 + bb.y * w21 + bb.z * w22 + bb.w * w23;
    }
  }
  float bz = benh[tid];
  float hv[16];
  #pragma unroll
  for (int r = 0; r < 16; ++r) hv[r] = fmaxf(acc[r] + bz, 0.f) + x2[r][tid];
  __syncthreads();
  #pragma unroll
  for (int r = 0; r < 16; ++r) x1[r][tid] = hv[r];
  __syncthreads();
  int w = tid >> 6, lane = tid & 63;
  for (int rr = 0; rr < 4; ++rr) {
    int r = w * 4 + rr;
    float s1 = 0.f, s2 = 0.f;
    #pragma unroll
    for (int jj = 0; jj < 4; ++jj) {
      float v = x1[r][lane + jj * 64];
      s1 += v; s2 += v * v;
    }
    #pragma unroll
    for (int off = 32; off; off >>= 1) {
      s1 += __shfl_xor(s1, off, 64);
      s2 += __shfl_xor(s2, off, 64);
    }
    if (lane == 0) {
      float mu = s1 * (1.f / 256.f);
      float var = s2 * (1.f / 256.f) - mu * mu;
      stats[r][0] = mu;
      stats[r][1] = rsqrtf(var + LN_EPS);
    }
  }
  __syncthreads();
  float gv = lng[tid], bv = lnb[tid];
  #pragma unroll
  for (int r = 0; r < 16; ++r) {
    float v = (x1[r][tid] - stats[r][0]) * stats[r][1] * gv + bv;
    outp[(size_t)(r0 + r) * ostride + obase + tid] = v;
  }
}

// ================= lin1: h1 = relu(pair @ W1_kn + b1) =================
__global__ __launch_bounds__(256) void k_lin(const float* __restrict__ X, const float* __restrict__ Wkn,
                                             const float* __restrict__ bias, float* __restrict__ Y,
                                             int Kdim, int Ndim, int act) {
  __shared__ float xs[16][512];
  int tid = threadIdx.x;
  int r0 = blockIdx.x * 16;
  int col = blockIdx.y * 256 + tid;
  for (int t = tid; t < 16 * Kdim; t += 256) {
    int r = t / Kdim, k = t - r * Kdim;
    xs[r][k] = X[(size_t)(r0 + r) * Kdim + k];
  }
  __syncthreads();
  float acc[16];
  #pragma unroll
  for (int r = 0; r < 16; ++r) acc[r] = 0.f;
  for (int k4 = 0; k4 < Kdim; k4 += 4) {
    float w0 = Wkn[(size_t)(k4 + 0) * Ndim + col];
    float w1 = Wkn[(size_t)(k4 + 1) * Ndim + col];
    float w2 = Wkn[(size_t)(k4 + 2) * Ndim + col];
    float w3 = Wkn[(size_t)(k4 + 3) * Ndim + col];
    #pragma unroll
    for (int r = 0; r < 16; ++r) {
      float4 a = *(const float4*)&xs[r][k4];
      acc[r] += a.x * w0 + a.y * w1 + a.z * w2 + a.w * w3;
    }
  }
  float bv = bias ? bias[col] : 0.f;
  #pragma unroll
  for (int r = 0; r < 16; ++r) {
    float v = acc[r] + bv;
    if (act) v = fmaxf(v, 0.f);
    Y[(size_t)(r0 + r) * Ndim + col] = v;
  }
}

// ================= lin2 + final LN fused =================
__global__ __launch_bounds__(256) void k_mlp2ln(const float* __restrict__ h1, const float* __restrict__ W2kn,
                                                const float* __restrict__ pairb, const float* __restrict__ g,
                                                const float* __restrict__ bb, float* __restrict__ out) {
  __shared__ float xs[16][512];
  __shared__ float stats[16][2];
  int bid = blockIdx.x, tid = threadIdx.x;
  int r0 = bid * 16;
  for (int t = tid; t < 16 * 512; t += 256) {
    int r = t >> 9, k = t & 511;
    xs[r][k] = h1[(size_t)(r0 + r) * 512 + k];
  }
  __syncthreads();
  float acc0[16], acc1[16];
  #pragma unroll
  for (int r = 0; r < 16; ++r) { acc0[r] = 0.f; acc1[r] = 0.f; }
  for (int k4 = 0; k4 < 512; k4 += 4) {
    float a0 = W2kn[(size_t)(k4 + 0) * 512 + tid];
    float a1 = W2kn[(size_t)(k4 + 1) * 512 + tid];
    float a2 = W2kn[(size_t)(k4 + 2) * 512 + tid];
    float a3 = W2kn[(size_t)(k4 + 3) * 512 + tid];
    float b0 = W2kn[(size_t)(k4 + 0) * 512 + tid + 256];
    float b1 = W2kn[(size_t)(k4 + 1) * 512 + tid + 256];
    float b2 = W2kn[(size_t)(k4 + 2) * 512 + tid + 256];
    float b3 = W2kn[(size_t)(k4 + 3) * 512 + tid + 256];
    #pragma unroll
    for (int r = 0; r < 16; ++r) {
      float4 a = *(const float4*)&xs[r][k4];
      acc0[r] += a.x * a0 + a.y * a1 + a.z * a2 + a.w * a3;
      acc1[r] += a.x * b0 + a.y * b1 + a.z * b2 + a.w * b3;
    }
  }
  __syncthreads();
  #pragma unroll
  for (int r = 0; r < 16; ++r) {
    xs[r][tid]       = acc0[r] + pairb[(size_t)(r0 + r) * 512 + tid];
    xs[r][tid + 256] = acc1[r] + pairb[(size_t)(r0 + r) * 512 + tid + 256];
  }
  __syncthreads();
  int w = tid >> 6, lane = tid & 63;
  for (int rr = 0; rr < 4; ++rr) {
    int r = w * 4 + rr;
    float s1 = 0.f, s2 = 0.f;
    #pragma unroll
    for (int jj = 0; jj < 8; ++jj) {
      float v = xs[r][lane + jj * 64];
      s1 += v; s2 += v * v;
    }
    #pragma unroll
    for (int off = 32; off; off >>= 1) {
      s1 += __shfl_xor(s1, off, 64);
      s2 += __shfl_xor(s2, off, 64);
    }
    if (lane == 0) {
      float mu = s1 * (1.f / 512.f);
      stats[r][0] = mu;
      stats[r][1] = rsqrtf(s2 * (1.f / 512.f) - mu * mu + LN_EPS);
    }
  }
  __syncthreads();
  float g0 = g[tid], g1 = g[tid + 256], b0v = bb[tid], b1v = bb[tid + 256];
  #pragma unroll
  for (int r = 0; r < 16; ++r) {
    float mu = stats[r][0], rstd = stats[r][1];
    out[(size_t)(r0 + r) * 512 + tid]       = (xs[r][tid] - mu) * rstd * g0 + b0v;
    out[(size_t)(r0 + r) * 512 + tid + 256] = (xs[r][tid + 256] - mu) * rstd * g1 + b1v;
  }
}

extern "C" void kernel_launch(void* const* d_in, const int* in_sizes, int n_in,
                              void* d_out, int out_size, void* d_ws, size_t ws_size,
                              hipStream_t stream) {
  (void)in_sizes; (void)n_in; (void)out_size; (void)ws_size;
  const int*   entity_pairs = (const int*)d_in[0];
  const int*   left_conn    = (const int*)d_in[1];
  const int*   right_conn   = (const int*)d_in[3];
  const float* emb    = (const float*)d_in[5];
  const float* Wq_t   = (const float*)d_in[6];
  const float* Wk_t   = (const float*)d_in[7];
  const float* Wv_t   = (const float*)d_in[8];
  const float* Wbil_t = (const float*)d_in[9];
  const float* Wo_t   = (const float*)d_in[10];
  const float* bo_t   = (const float*)d_in[11];
  const float* Wq_e   = (const float*)d_in[12];
  const float* Wk_e   = (const float*)d_in[13];
  const float* Wv_e   = (const float*)d_in[14];
  const float* Wbil_e = (const float*)d_in[15];
  const float* Wo_e   = (const float*)d_in[16];
  const float* bo_e   = (const float*)d_in[17];
  const float* ln_g   = (const float*)d_in[18];
  const float* ln_b   = (const float*)d_in[19];
  const float* Wtail  = (const float*)d_in[20];
  const float* Whead  = (const float*)d_in[21];
  const float* Wrel   = (const float*)d_in[22];
  const float* W1     = (const float*)d_in[23];
  const float* b1     = (const float*)d_in[24];
  const float* W2     = (const float*)d_in[25];
  const float* ln1_g  = (const float*)d_in[26];
  const float* ln1_b  = (const float*)d_in[27];
  const float* Wg     = (const float*)d_in[28];
  const float* Ug     = (const float*)d_in[29];
  const float* bg     = (const float*)d_in[30];
  const float* Wr     = (const float*)d_in[31];
  const float* Ur     = (const float*)d_in[32];
  const float* br     = (const float*)d_in[33];
  float* out = (float*)d_out;

  // ---- workspace layout ----
  char* wp = (char*)d_ws;
  auto alloc = [&](size_t bytes) -> void* {
    void* p = (void*)wp;
    wp += (bytes + 255) & ~(size_t)255;
    return p;
  };
  bf16* Wrel_bf = (bf16*)alloc((size_t)512 * 65536 * 2);
  bf16* emb_bf  = (bf16*)alloc((size_t)EMB_PAD * 256 * 2);
  bf16* E4      = (bf16*)alloc((size_t)EMB_PAD * 1024 * 2);
  bf16* wcat    = (bf16*)alloc((size_t)1024 * 256 * 2);
  bf16* Vh      = (bf16*)alloc((size_t)BN * MN * 256 * 2);
  bf16* Vt      = (bf16*)alloc((size_t)BN * MN * 256 * 2);
  bf16* eRbf_g  = (bf16*)alloc((size_t)BN * 256 * 2);
  float* eLT    = (float*)alloc((size_t)256 * BN * 4);
  float* eLp     = (float*)alloc((size_t)BN * 256 * 4);
  float* eRp     = (float*)alloc((size_t)BN * 256 * 4);
  float* bil_part= (float*)alloc((size_t)SPLITK * BN * 512 * 4);
  float* qkbuf   = (float*)alloc((size_t)2 * BN * 256 * 4);
  float* ovbuf   = (float*)alloc((size_t)2 * BN * 256 * 4);
  float* enh_h   = (float*)alloc((size_t)BN * 256 * 4);
  float* enh_t   = (float*)alloc((size_t)BN * 256 * 4);
  float* pairb   = (float*)alloc((size_t)BN * 512 * 4);
  float* h1buf   = (float*)alloc((size_t)BN * 512 * 4);
  float* T_t     = (float*)alloc(256 * 256 * 4);
  float* Cq_t    = (float*)alloc(256 * 256 * 4);
  float* Wov_t   = (float*)alloc(256 * 256 * 4);
  float* Wenh_t  = (float*)alloc(256 * 256 * 4);
  float* benh_t  = (float*)alloc(256 * 4);
  float* T_e     = (float*)alloc(256 * 256 * 4);
  float* Cq_e    = (float*)alloc(256 * 256 * 4);
  float* Wov_e   = (float*)alloc(256 * 256 * 4);
  float* Wenh_e  = (float*)alloc(256 * 256 * 4);
  float* benh_e  = (float*)alloc(256 * 4);
  float* Whead_kn= (float*)alloc(256 * 256 * 4);
  float* WtailT  = (float*)alloc(256 * 256 * 4);
  float* W1_kn   = (float*)alloc(512 * 512 * 4);
  float* W2_kn   = (float*)alloc(512 * 512 * 4);

  // ---- 1: all independent precompute ----
  k_stage1<<<S1_GRID, 256, 0, stream>>>(Wbil_t, Wq_t, Wbil_e, Wq_e, Wo_t, Wv_t, Wo_e, Wv_e,
                                        Wtail, Whead, W1, W2, Wg, Ug, Wr, Ur, Wrel, emb,
                                        entity_pairs,
                                        T_t, T_e, Wov_t, Wov_e, WtailT, Whead_kn, W1_kn, W2_kn,
                                        wcat, emb_bf, eLp, eRp, eRbf_g, eLT, Wrel_bf);
  // ---- 2: bilinear right after stage1 (Wrel_bf L3-warm; owns caches) ----
  k_bilinear<<<2048, 256, 0, stream>>>(eRbf_g, eLT, Wrel_bf, bil_part);
  // ---- 3: e4 (quadrant-LDS wcat, coalesced epilogue) + stage-2 weight products ----
  k_e4s2<<<4161, 256, 0, stream>>>(emb_bf, wcat, E4,
                                   T_t, Wk_t, Cq_t, T_e, Wk_e, Cq_e,
                                   Wov_t, WtailT, Wenh_t, Wov_e, Wenh_e,
                                   Wtail, bo_t, bo_e, benh_t, benh_e);
  // ---- 4: merged vbuild + qk12 ----
  k_vq<<<33024, 256, 0, stream>>>(left_conn, right_conn, emb_bf, E4, bg, br, Vh, Vt,
                                  bil_part, Cq_t, qkbuf);
  // ---- stage A: chains 1+2 ----
  k_attn_dual<<<4096, 256, 0, stream>>>(qkbuf, left_conn, right_conn, Vh, Vt, 0, emb_bf, ovbuf);
  k_enh_dual<<<256, 256, 0, stream>>>(ovbuf, eLp, eRp, Wenh_t, Whead_kn, benh_t, ln_g, ln_b,
                                      enh_h, enh_t, 256, 0, 0);
  // ---- stage B: chains 3+4 ----
  k_qk34<<<256, 256, 0, stream>>>(enh_t, enh_h, Cq_e, qkbuf);
  k_attn_dual<<<4096, 256, 0, stream>>>(qkbuf, left_conn, right_conn, Vh, Vt, 1, emb_bf, ovbuf);
  k_enh_dual<<<256, 256, 0, stream>>>(ovbuf, eLp, eRp, Wenh_e, Whead_kn, benh_e, ln_g, ln_b,
                                      pairb, pairb, 512, 0, 256);

  // ---- final MLP + LN ----
  k_lin<<<dim3(128, 2), 256, 0, stream>>>(pairb, W1_kn, b1, h1buf, 512, 512, 1);
  k_mlp2ln<<<128, 256, 0, stream>>>(h1buf, W2_kn, pairb, ln1_g, ln1_b, out);
}

// Round 13
// 859.459 us; speedup vs baseline: 1.0521x; 1.0521x over previous
//
#include <hip/hip_runtime.h>
#include <hip/hip_bf16.h>

// Problem constants
#define BN 2048
#define MN 64
#define DN 256
#define EMB_ROWS 50001
#define EMB_PAD 50016
#define LN_EPS 1e-5f
#define SPLITK 16
#define KCHUNK 4096   // 65536 / SPLITK

typedef __hip_bfloat16 bf16;
typedef __attribute__((ext_vector_type(8))) short bf16x8;
typedef __attribute__((ext_vector_type(4))) float f32x4;

static __device__ __forceinline__ short f2bf(float f) {
  return __builtin_bit_cast(short, __float2bfloat16(f));
}
static __device__ __forceinline__ float bfu(unsigned short u) {
  unsigned int x = ((unsigned int)u) << 16;
  return __builtin_bit_cast(float, x);
}
// fast sigmoid via v_exp_f32
static __device__ __forceinline__ float fsig(float x) {
  return 1.f / (1.f + __expf(-x));
}

typedef __attribute__((address_space(1))) const void g_void;
typedef __attribute__((address_space(3))) void l_void;
static __device__ __forceinline__ void gl_lds16(const void* g, void* l) {
  __builtin_amdgcn_global_load_lds((g_void*)g, (l_void*)l, 16, 0, 0);
}

// ---- device helpers for the batched precompute ----
static __device__ __forceinline__ void dev_mm(float* __restrict__ C, const float* __restrict__ A,
                                              const float* __restrict__ B, int N, int K,
                                              int aI, int aM, int bM, int bJ, int blk, int tid) {
  int idx = blk * 256 + tid;
  int i = idx / N, j = idx - i * N;
  float s = 0.f;
  for (int m = 0; m < K; ++m) s += A[i * aI + m * aM] * B[m * bM + j * bJ];
  C[idx] = s;
}
static __device__ __forceinline__ void dev_tr(float* __restrict__ dst, const float* __restrict__ src,
                                              int rows, int cols, int blk, int tid) {
  int idx = blk * 256 + tid;
  int r = idx / cols, c = idx - r * cols;
  dst[c * rows + r] = src[idx];
}

// ================= stage 1: all independent precompute in ONE launch =================
#define S1_GRID 27349
__global__ void k_stage1(const float* __restrict__ Wbil_t, const float* __restrict__ Wq_t,
                         const float* __restrict__ Wbil_e, const float* __restrict__ Wq_e,
                         const float* __restrict__ Wo_t, const float* __restrict__ Wv_t,
                         const float* __restrict__ Wo_e, const float* __restrict__ Wv_e,
                         const float* __restrict__ Wtail, const float* __restrict__ Whead,
                         const float* __restrict__ W1, const float* __restrict__ W2,
                         const float* __restrict__ Wg, const float* __restrict__ Ug,
                         const float* __restrict__ Wr, const float* __restrict__ Ur,
                         const float* __restrict__ Wrel, const float* __restrict__ emb,
                         const int* __restrict__ pairs,
                         float* __restrict__ T_t, float* __restrict__ T_e,
                         float* __restrict__ Wov_t, float* __restrict__ Wov_e,
                         float* __restrict__ WtailT, float* __restrict__ Whead_kn,
                         float* __restrict__ W1_kn, float* __restrict__ W2_kn,
                         bf16* __restrict__ wcat, bf16* __restrict__ emb_bf,
                         float* __restrict__ eL, float* __restrict__ eR,
                         bf16* __restrict__ eRbf, float* __restrict__ eLT,
                         bf16* __restrict__ Wrel_bf) {
  int bid = blockIdx.x, tid = threadIdx.x;
  if (bid < 256)        dev_mm(T_t, Wbil_t, Wq_t, 256, 256, 256, 1, 256, 1, bid, tid);
  else if (bid < 512)   dev_mm(T_e, Wbil_e, Wq_e, 256, 256, 256, 1, 256, 1, bid - 256, tid);
  else if (bid < 768)   dev_mm(Wov_t, Wo_t, Wv_t, 256, 256, 256, 1, 256, 1, bid - 512, tid);
  else if (bid < 1024)  dev_mm(Wov_e, Wo_e, Wv_e, 256, 256, 256, 1, 256, 1, bid - 768, tid);
  else if (bid < 1280)  dev_tr(WtailT, Wtail, 256, 256, bid - 1024, tid);
  else if (bid < 1536)  dev_tr(Whead_kn, Whead, 256, 256, bid - 1280, tid);
  else if (bid < 2560)  dev_tr(W1_kn, W1, 512, 512, bid - 1536, tid);
  else if (bid < 3584)  dev_tr(W2_kn, W2, 512, 512, bid - 2560, tid);
  else if (bid < 4608) {            // wcat bf16 [n][k] = W[k][n] for [Wg|Ug|Wr|Ur]
    int idx = (bid - 3584) * 256 + tid;
    int n = idx >> 8, k = idx & 255;
    const float* s = (n < 256) ? Wg : (n < 512) ? Ug : (n < 768) ? Wr : Ur;
    wcat[idx] = __float2bfloat16(s[k * 256 + (n & 255)]);
  } else if (bid < 17109) {         // emb f32 -> bf16
    int i = (bid - 4608) * 256 + tid;
    if (i < (EMB_ROWS * 256) / 4) {
      float4 v = ((const float4*)emb)[i];
      ushort4 o;
      o.x = (unsigned short)f2bf(v.x); o.y = (unsigned short)f2bf(v.y);
      o.z = (unsigned short)f2bf(v.z); o.w = (unsigned short)f2bf(v.w);
      ((ushort4*)emb_bf)[i] = o;
    }
  } else if (bid < 19157) {         // gather eL/eR (+bf16 eR, transposed eL)
    int b = bid - 17109, d = tid;
    float vL = emb[(size_t)pairs[2 * b] * 256 + d];
    float vR = emb[(size_t)pairs[2 * b + 1] * 256 + d];
    eL[b * 256 + d] = vL;
    eR[b * 256 + d] = vR;
    eRbf[b * 256 + d] = __float2bfloat16(vR);
    eLT[(size_t)d * BN + b] = vL;
  } else {                          // Wrel f32 -> bf16
    int blk = bid - 19157;
    int base = blk * 1024 + tid;
    #pragma unroll
    for (int it = 0; it < 4; ++it) {
      int i = base + it * 256;
      float4 v = ((const float4*)Wrel)[i];
      ushort4 o;
      o.x = (unsigned short)f2bf(v.x); o.y = (unsigned short)f2bf(v.y);
      o.z = (unsigned short)f2bf(v.z); o.w = (unsigned short)f2bf(v.w);
      ((ushort4*)Wrel_bf)[i] = o;
    }
  }
}

// ================= bilinear: PROVEN 2-phase double-buffer (R5/R8: ~160us, FETCH 45MB) =================
// Lockstep drain rate-matches the 16 bx-sibling blocks per XCD so Wrel tiles stay
// L2-resident. Do NOT pipeline (R7); (256,3) tested neutral (R12) -> keep proven (256,2).
__global__ __launch_bounds__(256, 2) void k_bilinear(const bf16* __restrict__ eRbf,
                                                     const float* __restrict__ eLT,
                                                     const bf16* __restrict__ wrel,
                                                     float* __restrict__ part) {
  __shared__ char bsh[2][8192];   // 2 x (64 rows x 64 bf16)
  int bid = blockIdx.x;
  int lid = (bid & 7) * 256 + (bid >> 3);   // bijective XCD swizzle (2048 % 8 == 0)
  int bx = lid & 15, by = (lid >> 4) & 7, bz = lid >> 7;
  int tid = threadIdx.x, w = tid >> 6, lane = tid & 63;
  int l16 = lane & 15, lq = lane >> 4;
  int kfo = lq * 8;
  int m_base = bx * 128 + w * 32;
  int n0 = by * 64;
  int i0 = bz * 16;

  bf16x8 ar[2][8];
  #pragma unroll
  for (int mi = 0; mi < 2; ++mi) {
    const bf16* er = eRbf + (size_t)(m_base + mi * 16 + l16) * 256 + kfo;
    #pragma unroll
    for (int jb = 0; jb < 8; ++jb) ar[mi][jb] = *(const bf16x8*)(er + jb * 32);
  }

  f32x4 z = {0.f, 0.f, 0.f, 0.f};
  f32x4 accF[2][4];
  f32x4 P[2][4];
  #pragma unroll
  for (int mi = 0; mi < 2; ++mi)
    #pragma unroll
    for (int nf = 0; nf < 4; ++nf) { accF[mi][nf] = z; P[mi][nf] = z; }

  int srow = tid >> 3, sblk = tid & 7;
  const bf16* wbase = wrel + (size_t)n0 * 65536 + (size_t)i0 * 256;
  auto stage = [&](int c, int step) {
    size_t so = (size_t)step * 64;
    #pragma unroll
    for (int q = 0; q < 2; ++q) {
      int r = q * 32 + srow;
      const bf16* src = wbase + (size_t)r * 65536 + so + (size_t)((sblk ^ (r & 7)) << 3);
      gl_lds16(src, &bsh[c][q * 4096 + w * 1024]);
    }
  };

  stage(0, 0);
  __syncthreads();
  int cur = 0;
  for (int s = 0; s < 16; ++s) {
    const float* elb = eLT + (size_t)(i0 + s) * BN + m_base + lq * 4;
    float4 el0 = *(const float4*)(elb);
    float4 el1 = *(const float4*)(elb + 16);
    #pragma unroll
    for (int jb4 = 0; jb4 < 4; ++jb4) {
      int step = s * 4 + jb4;
      if (step + 1 < 64) stage(cur ^ 1, step + 1);
      bf16x8 bq[2][4];
      #pragma unroll
      for (int kk = 0; kk < 2; ++kk)
        #pragma unroll
        for (int nf = 0; nf < 4; ++nf) {
          int rl = nf * 16 + l16;
          int blk = (kk * 4 + lq) ^ (l16 & 7);
          bq[kk][nf] = *(const bf16x8*)&bsh[cur][rl * 128 + (blk << 4)];
        }
      #pragma unroll
      for (int kk = 0; kk < 2; ++kk)
        #pragma unroll
        for (int mi = 0; mi < 2; ++mi)
          #pragma unroll
          for (int nf = 0; nf < 4; ++nf) {
            if (jb4 == 0 && kk == 0)
              P[mi][nf] = __builtin_amdgcn_mfma_f32_16x16x32_bf16(ar[mi][jb4 * 2 + kk], bq[kk][nf], z, 0, 0, 0);
            else
              P[mi][nf] = __builtin_amdgcn_mfma_f32_16x16x32_bf16(ar[mi][jb4 * 2 + kk], bq[kk][nf], P[mi][nf], 0, 0, 0);
          }
      __syncthreads();
      cur ^= 1;
    }
    #pragma unroll
    for (int mi = 0; mi < 2; ++mi) {
      float4 el = mi ? el1 : el0;
      #pragma unroll
      for (int nf = 0; nf < 4; ++nf) {
        accF[mi][nf][0] += el.x * P[mi][nf][0];
        accF[mi][nf][1] += el.y * P[mi][nf][1];
        accF[mi][nf][2] += el.z * P[mi][nf][2];
        accF[mi][nf][3] += el.w * P[mi][nf][3];
      }
    }
  }

  float* p = part + (size_t)bz * BN * 512;
  #pragma unroll
  for (int mi = 0; mi < 2; ++mi) {
    #pragma unroll
    for (int nf = 0; nf < 4; ++nf) {
      int col = n0 + nf * 16 + l16;
      #pragma unroll
      for (int r = 0; r < 4; ++r) {
        int row = m_base + mi * 16 + lq * 4 + r;
        p[(size_t)row * 512 + col] = accF[mi][nf][r];
      }
    }
  }
}

// ================= e4 body v4: quadrant LDS + coalesced epilogue (R10-proven) ====
static __device__ __forceinline__ void dev_e4(char* wsh, char* tb, int bid,
                                              const bf16* __restrict__ embbf,
                                              const bf16* __restrict__ wcat, bf16* __restrict__ E4) {
  int lid = (bid & 7) * 392 + (bid >> 3);   // bijective: 3136 = 8*392
  int mchunk = lid >> 4, nt = lid & 15;
  int tid = threadIdx.x;
  int w = tid >> 6, lane = tid & 63;
  int l16 = lane & 15, lq = lane >> 4, kfo = lq * 8;
  int n0 = nt * 64;

  #pragma unroll
  for (int issue = 0; issue < 8; ++issue) {
    int L = issue * 4096 + tid * 16;
    int q = L >> 13;
    int rl = (L >> 7) & 63;
    int blk = (L >> 4) & 7;
    const bf16* src = wcat + (size_t)(n0 + rl) * 256 + q * 64 + ((blk ^ (rl & 7)) << 3);
    gl_lds16(src, wsh + L);
  }
  __syncthreads();

  char* tw = tb + w * 2176;   // per-wave transpose buffer: 16 rows x 136B
  int trow = lane >> 2, tc = lane & 3;
  f32x4 z = {0.f, 0.f, 0.f, 0.f};
  #pragma unroll
  for (int g = 0; g < 4; ++g) {
    int rbase = mchunk * 256 + w * 64 + g * 16;
    int arow = rbase + l16; if (arow >= EMB_ROWS) arow = EMB_ROWS - 1;
    const bf16* ap = embbf + (size_t)arow * 256 + kfo;
    bf16x8 A[8];
    #pragma unroll
    for (int ks = 0; ks < 8; ++ks) A[ks] = *(const bf16x8*)(ap + ks * 32);
    f32x4 acc[4];
    #pragma unroll
    for (int nf = 0; nf < 4; ++nf) acc[nf] = z;
    #pragma unroll
    for (int ks = 0; ks < 8; ++ks) {
      int qd = ks >> 1, kk = ks & 1;
      bf16x8 bq[4];
      #pragma unroll
      for (int nf = 0; nf < 4; ++nf) {
        int rl = nf * 16 + l16;
        int blk = (kk * 4 + lq) ^ (l16 & 7);
        bq[nf] = *(const bf16x8*)&wsh[qd * 8192 + rl * 128 + (blk << 4)];
      }
      acc[0] = __builtin_amdgcn_mfma_f32_16x16x32_bf16(A[ks], bq[0], acc[0], 0, 0, 0);
      acc[1] = __builtin_amdgcn_mfma_f32_16x16x32_bf16(A[ks], bq[1], acc[1], 0, 0, 0);
      acc[2] = __builtin_amdgcn_mfma_f32_16x16x32_bf16(A[ks], bq[2], acc[2], 0, 0, 0);
      acc[3] = __builtin_amdgcn_mfma_f32_16x16x32_bf16(A[ks], bq[3], acc[3], 0, 0, 0);
    }
    #pragma unroll
    for (int nf = 0; nf < 4; ++nf)
      #pragma unroll
      for (int r = 0; r < 4; ++r)
        *(bf16*)(tw + (lq * 4 + r) * 136 + (nf * 16 + l16) * 2) = __float2bfloat16(acc[nf][r]);
    int orow = rbase + trow;
    #pragma unroll
    for (int it = 0; it < 2; ++it) {
      bf16x8 vv = *(const bf16x8*)(tw + trow * 136 + (tc + 4 * it) * 16);
      if (orow < EMB_ROWS)
        *(bf16x8*)(E4 + (size_t)orow * 1024 + n0 + (tc + 4 * it) * 8) = vv;
    }
  }
}

// ================= e4 + stage2 weight products =================
__global__ __launch_bounds__(256, 2) void k_e4s2(const bf16* __restrict__ embbf, const bf16* __restrict__ wcat,
                                                 bf16* __restrict__ E4,
                                                 const float* __restrict__ T_t, const float* __restrict__ Wk_t,
                                                 float* __restrict__ Cq_t,
                                                 const float* __restrict__ T_e, const float* __restrict__ Wk_e,
                                                 float* __restrict__ Cq_e,
                                                 const float* __restrict__ Wov_t, const float* __restrict__ WtailT,
                                                 float* __restrict__ Wenh_t,
                                                 const float* __restrict__ Wov_e, float* __restrict__ Wenh_e,
                                                 const float* __restrict__ Wtail, const float* __restrict__ bo_t,
                                                 const float* __restrict__ bo_e,
                                                 float* __restrict__ benh_t, float* __restrict__ benh_e) {
  __shared__ char wsh[32768 + 4 * 2176];
  int bid = blockIdx.x, tid = threadIdx.x;
  if (bid < 3136) {
    dev_e4(wsh, wsh + 32768, bid, embbf, wcat, E4);
    return;
  }
  int b2 = bid - 3136;
  if (b2 < 256)       dev_mm(Cq_t, T_t, Wk_t, 256, 256, 1, 256, 256, 1, b2, tid);
  else if (b2 < 512)  dev_mm(Cq_e, T_e, Wk_e, 256, 256, 1, 256, 256, 1, b2 - 256, tid);
  else if (b2 < 768)  dev_mm(Wenh_t, Wov_t, WtailT, 256, 256, 1, 256, 256, 1, b2 - 512, tid);
  else if (b2 < 1024) dev_mm(Wenh_e, Wov_e, WtailT, 256, 256, 1, 256, 256, 1, b2 - 768, tid);
  else {
    float s1 = 0.f, s2 = 0.f;
    for (int m = 0; m < 256; ++m) {
      float wv = Wtail[tid * 256 + m];
      s1 += wv * bo_t[m];
      s2 += wv * bo_e[m];
    }
    benh_t[tid] = s1;
    benh_e[tid] = s2;
  }
}

// ================= merged qk12 + vbuild (qk12 FIRST: heavy blocks overlap the vbuild sea,
// instead of running as a serial 256-block tail at 1 block/CU — R12 theory) =================
static __device__ __forceinline__ void dev_vbuild(int bid, const int* __restrict__ lconn,
                                                  const int* __restrict__ rconn,
                                                  const bf16* __restrict__ embbf, const bf16* __restrict__ E4,
                                                  const float* __restrict__ bg, const float* __restrict__ br,
                                                  bf16* __restrict__ Vh, bf16* __restrict__ Vt) {
  int task = bid * 4 + (threadIdx.x >> 6);
  int lane = threadIdx.x & 63;
  int d0 = lane * 4;
  int i0 = lconn[2 * task], i1 = lconn[2 * task + 1];
  int r0 = rconn[2 * task], r1 = rconn[2 * task + 1];
  ushort4 Lga = *(const ushort4*)(E4 + (size_t)i0 * 1024 + d0);
  ushort4 Lgb = *(const ushort4*)(E4 + (size_t)i1 * 1024 + 256 + d0);
  ushort4 Lea = *(const ushort4*)(embbf + (size_t)i0 * 256 + d0);
  ushort4 Leb = *(const ushort4*)(embbf + (size_t)i1 * 256 + d0);
  ushort4 Rga = *(const ushort4*)(E4 + (size_t)r0 * 1024 + 512 + d0);
  ushort4 Rgb = *(const ushort4*)(E4 + (size_t)r1 * 1024 + 768 + d0);
  ushort4 Rea = *(const ushort4*)(embbf + (size_t)r0 * 256 + d0);
  ushort4 Reb = *(const ushort4*)(embbf + (size_t)r1 * 256 + d0);
  float4 bgv = *(const float4*)(bg + d0);
  float4 brv = *(const float4*)(br + d0);
  ushort4 oh, ot;
  {
    float g = fsig(bfu(Lga.x) + bfu(Lgb.x) + bgv.x);
    oh.x = (unsigned short)f2bf(fmaxf(g * bfu(Lea.x) + (1.f - g) * bfu(Leb.x), 0.f));
    g = fsig(bfu(Lga.y) + bfu(Lgb.y) + bgv.y);
    oh.y = (unsigned short)f2bf(fmaxf(g * bfu(Lea.y) + (1.f - g) * bfu(Leb.y), 0.f));
    g = fsig(bfu(Lga.z) + bfu(Lgb.z) + bgv.z);
    oh.z = (unsigned short)f2bf(fmaxf(g * bfu(Lea.z) + (1.f - g) * bfu(Leb.z), 0.f));
    g = fsig(bfu(Lga.w) + bfu(Lgb.w) + bgv.w);
    oh.w = (unsigned short)f2bf(fmaxf(g * bfu(Lea.w) + (1.f - g) * bfu(Leb.w), 0.f));
  }
  {
    float g = fsig(bfu(Rga.x) + bfu(Rgb.x) + brv.x);
    ot.x = (unsigned short)f2bf(fmaxf(g * bfu(Rea.x) + (1.f - g) * bfu(Reb.x), 0.f));
    g = fsig(bfu(Rga.y) + bfu(Rgb.y) + brv.y);
    ot.y = (unsigned short)f2bf(fmaxf(g * bfu(Rea.y) + (1.f - g) * bfu(Reb.y), 0.f));
    g = fsig(bfu(Rga.z) + bfu(Rgb.z) + brv.z);
    ot.z = (unsigned short)f2bf(fmaxf(g * bfu(Rea.z) + (1.f - g) * bfu(Reb.z), 0.f));
    g = fsig(bfu(Rga.w) + bfu(Rgb.w) + brv.w);
    ot.w = (unsigned short)f2bf(fmaxf(g * bfu(Rea.w) + (1.f - g) * bfu(Reb.w), 0.f));
  }
  *(ushort4*)(Vh + (size_t)task * 256 + d0) = oh;
  *(ushort4*)(Vt + (size_t)task * 256 + d0) = ot;
}

__global__ __launch_bounds__(256) void k_vq(const int* __restrict__ lconn, const int* __restrict__ rconn,
                                            const bf16* __restrict__ embbf, const bf16* __restrict__ E4,
                                            const float* __restrict__ bg, const float* __restrict__ br,
                                            bf16* __restrict__ Vh, bf16* __restrict__ Vt,
                                            const float* __restrict__ part, const float* __restrict__ Cq,
                                            float* __restrict__ qkb) {
  __shared__ float xs[16][256];
  int bid = blockIdx.x, tid = threadIdx.x;
  if (bid >= 256) {
    dev_vbuild(bid - 256, lconn, rconn, embbf, E4, bg, br, Vh, Vt);
    return;
  }
  // qk12: inline split-K reduce + Cq matmul (chains 1+2) — first in dispatch order
  int b2 = bid;
  int half = b2 >> 7;
  int r0 = (b2 & 127) * 16;
  int col0 = half * 256;
  for (int t = tid; t < 16 * 256; t += 256) {
    int r = t >> 8, k = t & 255;
    const float* pp = part + (size_t)(r0 + r) * 512 + col0 + k;
    float s = 0.f;
    #pragma unroll
    for (int zc = 0; zc < SPLITK; ++zc) s += pp[(size_t)zc * BN * 512];
    xs[r][k] = s;
  }
  __syncthreads();
  float acc[16];
  #pragma unroll
  for (int r = 0; r < 16; ++r) acc[r] = 0.f;
  for (int k4 = 0; k4 < 256; k4 += 4) {
    float w0 = Cq[(k4 + 0) * 256 + tid];
    float w1 = Cq[(k4 + 1) * 256 + tid];
    float w2 = Cq[(k4 + 2) * 256 + tid];
    float w3 = Cq[(k4 + 3) * 256 + tid];
    #pragma unroll
    for (int r = 0; r < 16; ++r) {
      float4 a = *(const float4*)&xs[r][k4];
      acc[r] += a.x * w0 + a.y * w1 + a.z * w2 + a.w * w3;
    }
  }
  int ob = half * 2048 + r0;
  #pragma unroll
  for (int r = 0; r < 16; ++r) qkb[(size_t)(ob + r) * 256 + tid] = acc[r];
}

// ================= qk stage B: two-input Cq matmul (chains 3+4) =================
__global__ __launch_bounds__(256) void k_qk34(const float* __restrict__ X0, const float* __restrict__ X1,
                                              const float* __restrict__ Cq, float* __restrict__ qkb) {
  __shared__ float xs[16][256];
  int bid = blockIdx.x, tid = threadIdx.x;
  int half = bid >> 7;
  const float* X = half ? X1 : X0;
  int r0 = (bid & 127) * 16;
  for (int t = tid; t < 16 * 256; t += 256) {
    int r = t >> 8, k = t & 255;
    xs[r][k] = X[(size_t)(r0 + r) * 256 + k];
  }
  __syncthreads();
  float acc[16];
  #pragma unroll
  for (int r = 0; r < 16; ++r) acc[r] = 0.f;
  for (int k4 = 0; k4 < 256; k4 += 4) {
    float w0 = Cq[(k4 + 0) * 256 + tid];
    float w1 = Cq[(k4 + 1) * 256 + tid];
    float w2 = Cq[(k4 + 2) * 256 + tid];
    float w3 = Cq[(k4 + 3) * 256 + tid];
    #pragma unroll
    for (int r = 0; r < 16; ++r) {
      float4 a = *(const float4*)&xs[r][k4];
      acc[r] += a.x * w0 + a.y * w1 + a.z * w2 + a.w * w3;
    }
  }
  int ob = half * 2048 + r0;
  #pragma unroll
  for (int r = 0; r < 16; ++r) qkb[(size_t)(ob + r) * 256 + tid] = acc[r];
}

// ================= dual-chain factorized attention (grid 4096) =================
__global__ __launch_bounds__(256) void k_attn_dual(const float* __restrict__ qk,
                                                   const int* __restrict__ lconn, const int* __restrict__ rconn,
                                                   const bf16* __restrict__ Vh, const bf16* __restrict__ Vt,
                                                   int sel, const bf16* __restrict__ embbf,
                                                   float* __restrict__ ov) {
  __shared__ float ss[64];
  __shared__ float as[64];
  __shared__ float ps[4][256];
  int bid = blockIdx.x;
  int b = bid & 2047;
  const int* conn = (bid < 2048) ? lconn : rconn;
  const bf16* Vbuf = (bid < 2048) ? Vh : Vt;
  int tid = threadIdx.x;
  int w = tid >> 6, lane = tid & 63;
  float4 qv = *(const float4*)(qk + (size_t)bid * 256 + lane * 4);
  for (int mi = 0; mi < 16; ++mi) {
    int m = w * 16 + mi;
    int idx = conn[((size_t)b * 64 + m) * 2 + sel];
    ushort4 kr = *(const ushort4*)(embbf + (size_t)idx * 256 + lane * 4);
    float p = qv.x * bfu(kr.x) + qv.y * bfu(kr.y) + qv.z * bfu(kr.z) + qv.w * bfu(kr.w);
    #pragma unroll
    for (int off = 32; off; off >>= 1) p += __shfl_xor(p, off, 64);
    if (lane == 0) ss[m] = p;
  }
  __syncthreads();
  if (w == 0) {
    float v = ss[lane];
    float mx = v;
    #pragma unroll
    for (int off = 32; off; off >>= 1) mx = fmaxf(mx, __shfl_xor(mx, off, 64));
    float e = __expf(v - mx);
    float sum = e;
    #pragma unroll
    for (int off = 32; off; off >>= 1) sum += __shfl_xor(sum, off, 64);
    as[lane] = e / sum;
  }
  __syncthreads();
  const bf16* vrow = Vbuf + (size_t)b * 64 * 256;
  float4 a4 = {0.f, 0.f, 0.f, 0.f};
  for (int mi = 0; mi < 16; ++mi) {
    int m = w * 16 + mi;
    float sc = as[m];
    ushort4 v4 = *(const ushort4*)(vrow + (size_t)m * 256 + lane * 4);
    a4.x += sc * bfu(v4.x);
    a4.y += sc * bfu(v4.y);
    a4.z += sc * bfu(v4.z);
    a4.w += sc * bfu(v4.w);
  }
  *(float4*)&ps[w][lane * 4] = a4;
  __syncthreads();
  float o = ps[0][tid] + ps[1][tid] + ps[2][tid] + ps[3][tid];
  ov[(size_t)bid * 256 + tid] = o;
}

// ================= dual-chain fused enhance (grid 256) =================
__global__ __launch_bounds__(256) void k_enh_dual(const float* __restrict__ ovb,
                                                  const float* __restrict__ e0, const float* __restrict__ e1,
                                                  const float* __restrict__ Wenh_kn, const float* __restrict__ Whead_kn,
                                                  const float* __restrict__ benh, const float* __restrict__ lng,
                                                  const float* __restrict__ lnb,
                                                  float* __restrict__ out0, float* __restrict__ out1,
                                                  int ostride, int ob0, int ob1) {
  __shared__ float x1[16][256];
  __shared__ float x2[16][256];
  __shared__ float stats[16][2];
  int bid = blockIdx.x, tid = threadIdx.x;
  int half = bid >> 7;
  const float* e = half ? e1 : e0;
  float* outp = half ? out1 : out0;
  int obase = half ? ob1 : ob0;
  int r0 = (bid & 127) * 16;
  int ovr0 = half * 2048 + r0;
  for (int t = tid; t < 16 * 256; t += 256) {
    int r = t >> 8, k = t & 255;
    x1[r][k] = ovb[(size_t)(ovr0 + r) * 256 + k];
    x2[r][k] = e[(size_t)(r0 + r) * 256 + k];
  }
  __syncthreads();
  float acc[16];
  #pragma unroll
  for (int r = 0; r < 16; ++r) acc[r] = 0.f;
  for (int k4 = 0; k4 < 256; k4 += 4) {
    float w10 = Wenh_kn[(k4 + 0) * 256 + tid], w11 = Wenh_kn[(k4 + 1) * 256 + tid];
    float w12 = Wenh_kn[(k4 + 2) * 256 + tid], w13 = Wenh_kn[(k4 + 3) * 256 + tid];
    float w20 = Whead_kn[(k4 + 0) * 256 + tid], w21 = Whead_kn[(k4 + 1) * 256 + tid];
    float w22 = Whead_kn[(k4 + 2) * 256 + tid], w23 = Whead_kn[(k4 + 3) * 256 + tid];
    #pragma unroll
    for (int r = 0; r < 16; ++r) {
      float4 a = *(const float4*)&x1[r][k4];
      float4 bb = *(const float4*)&x2[r][k4];
      acc[r] += a.x * w10 + a.y * w11 + a.z * w12 + a.w * w13
              + bb.x * w20 + bb.y * w21 + bb.z * w22 + bb.w * w23;
    }
  }
  float bz = benh[tid];
  float hv[16];
  #pragma unroll
  for (int r = 0; r < 16; ++r) hv[r] = fmaxf(acc[r] + bz, 0.f) + x2[r][tid];
  __syncthreads();
  #pragma unroll
  for (int r = 0; r < 16; ++r) x1[r][tid] = hv[r];
  __syncthreads();
  int w = tid >> 6, lane = tid & 63;
  for (int rr = 0; rr < 4; ++rr) {
    int r = w * 4 + rr;
    float s1 = 0.f, s2 = 0.f;
    #pragma unroll
    for (int jj = 0; jj < 4; ++jj) {
      float v = x1[r][lane + jj * 64];
      s1 += v; s2 += v * v;
    }
    #pragma unroll
    for (int off = 32; off; off >>= 1) {
      s1 += __shfl_xor(s1, off, 64);
      s2 += __shfl_xor(s2, off, 64);
    }
    if (lane == 0) {
      float mu = s1 * (1.f / 256.f);
      float var = s2 * (1.f / 256.f) - mu * mu;
      stats[r][0] = mu;
      stats[r][1] = rsqrtf(var + LN_EPS);
    }
  }
  __syncthreads();
  float gv = lng[tid], bv = lnb[tid];
  #pragma unroll
  for (int r = 0; r < 16; ++r) {
    float v = (x1[r][tid] - stats[r][0]) * stats[r][1] * gv + bv;
    outp[(size_t)(r0 + r) * ostride + obase + tid] = v;
  }
}

// ================= lin1: h1 = relu(pair @ W1_kn + b1) =================
__global__ __launch_bounds__(256) void k_lin(const float* __restrict__ X, const float* __restrict__ Wkn,
                                             const float* __restrict__ bias, float* __restrict__ Y,
                                             int Kdim, int Ndim, int act) {
  __shared__ float xs[16][512];
  int tid = threadIdx.x;
  int r0 = blockIdx.x * 16;
  int col = blockIdx.y * 256 + tid;
  for (int t = tid; t < 16 * Kdim; t += 256) {
    int r = t / Kdim, k = t - r * Kdim;
    xs[r][k] = X[(size_t)(r0 + r) * Kdim + k];
  }
  __syncthreads();
  float acc[16];
  #pragma unroll
  for (int r = 0; r < 16; ++r) acc[r] = 0.f;
  for (int k4 = 0; k4 < Kdim; k4 += 4) {
    float w0 = Wkn[(size_t)(k4 + 0) * Ndim + col];
    float w1 = Wkn[(size_t)(k4 + 1) * Ndim + col];
    float w2 = Wkn[(size_t)(k4 + 2) * Ndim + col];
    float w3 = Wkn[(size_t)(k4 + 3) * Ndim + col];
    #pragma unroll
    for (int r = 0; r < 16; ++r) {
      float4 a = *(const float4*)&xs[r][k4];
      acc[r] += a.x * w0 + a.y * w1 + a.z * w2 + a.w * w3;
    }
  }
  float bv = bias ? bias[col] : 0.f;
  #pragma unroll
  for (int r = 0; r < 16; ++r) {
    float v = acc[r] + bv;
    if (act) v = fmaxf(v, 0.f);
    Y[(size_t)(r0 + r) * Ndim + col] = v;
  }
}

// ================= lin2 + final LN fused =================
__global__ __launch_bounds__(256) void k_mlp2ln(const float* __restrict__ h1, const float* __restrict__ W2kn,
                                                const float* __restrict__ pairb, const float* __restrict__ g,
                                                const float* __restrict__ bb, float* __restrict__ out) {
  __shared__ float xs[16][512];
  __shared__ float stats[16][2];
  int bid = blockIdx.x, tid = threadIdx.x;
  int r0 = bid * 16;
  for (int t = tid; t < 16 * 512; t += 256) {
    int r = t >> 9, k = t & 511;
    xs[r][k] = h1[(size_t)(r0 + r) * 512 + k];
  }
  __syncthreads();
  float acc0[16], acc1[16];
  #pragma unroll
  for (int r = 0; r < 16; ++r) { acc0[r] = 0.f; acc1[r] = 0.f; }
  for (int k4 = 0; k4 < 512; k4 += 4) {
    float a0 = W2kn[(size_t)(k4 + 0) * 512 + tid];
    float a1 = W2kn[(size_t)(k4 + 1) * 512 + tid];
    float a2 = W2kn[(size_t)(k4 + 2) * 512 + tid];
    float a3 = W2kn[(size_t)(k4 + 3) * 512 + tid];
    float b0 = W2kn[(size_t)(k4 + 0) * 512 + tid + 256];
    float b1 = W2kn[(size_t)(k4 + 1) * 512 + tid + 256];
    float b2 = W2kn[(size_t)(k4 + 2) * 512 + tid + 256];
    float b3 = W2kn[(size_t)(k4 + 3) * 512 + tid + 256];
    #pragma unroll
    for (int r = 0; r < 16; ++r) {
      float4 a = *(const float4*)&xs[r][k4];
      acc0[r] += a.x * a0 + a.y * a1 + a.z * a2 + a.w * a3;
      acc1[r] += a.x * b0 + a.y * b1 + a.z * b2 + a.w * b3;
    }
  }
  __syncthreads();
  #pragma unroll
  for (int r = 0; r < 16; ++r) {
    xs[r][tid]       = acc0[r] + pairb[(size_t)(r0 + r) * 512 + tid];
    xs[r][tid + 256] = acc1[r] + pairb[(size_t)(r0 + r) * 512 + tid + 256];
  }
  __syncthreads();
  int w = tid >> 6, lane = tid & 63;
  for (int rr = 0; rr < 4; ++rr) {
    int r = w * 4 + rr;
    float s1 = 0.f, s2 = 0.f;
    #pragma unroll
    for (int jj = 0; jj < 8; ++jj) {
      float v = xs[r][lane + jj * 64];
      s1 += v; s2 += v * v;
    }
    #pragma unroll
    for (int off = 32; off; off >>= 1) {
      s1 += __shfl_xor(s1, off, 64);
      s2 += __shfl_xor(s2, off, 64);
    }
    if (lane == 0) {
      float mu = s1 * (1.f / 512.f);
      stats[r][0] = mu;
      stats[r][1] = rsqrtf(s2 * (1.f / 512.f) - mu * mu + LN_EPS);
    }
  }
  __syncthreads();
  float g0 = g[tid], g1 = g[tid + 256], b0v = bb[tid], b1v = bb[tid + 256];
  #pragma unroll
  for (int r = 0; r < 16; ++r) {
    float mu = stats[r][0], rstd = stats[r][1];
    out[(size_t)(r0 + r) * 512 + tid]       = (xs[r][tid] - mu) * rstd * g0 + b0v;
    out[(size_t)(r0 + r) * 512 + tid + 256] = (xs[r][tid + 256] - mu) * rstd * g1 + b1v;
  }
}

extern "C" void kernel_launch(void* const* d_in, const int* in_sizes, int n_in,
                              void* d_out, int out_size, void* d_ws, size_t ws_size,
                              hipStream_t stream) {
  (void)in_sizes; (void)n_in; (void)out_size; (void)ws_size;
  const int*   entity_pairs = (const int*)d_in[0];
  const int*   left_conn    = (const int*)d_in[1];
  const int*   right_conn   = (const int*)d_in[3];
  const float* emb    = (const float*)d_in[5];
  const float* Wq_t   = (const float*)d_in[6];
  const float* Wk_t   = (const float*)d_in[7];
  const float* Wv_t   = (const float*)d_in[8];
  const float* Wbil_t = (const float*)d_in[9];
  const float* Wo_t   = (const float*)d_in[10];
  const float* bo_t   = (const float*)d_in[11];
  const float* Wq_e   = (const float*)d_in[12];
  const float* Wk_e   = (const float*)d_in[13];
  const float* Wv_e   = (const float*)d_in[14];
  const float* Wbil_e = (const float*)d_in[15];
  const float* Wo_e   = (const float*)d_in[16];
  const float* bo_e   = (const float*)d_in[17];
  const float* ln_g   = (const float*)d_in[18];
  const float* ln_b   = (const float*)d_in[19];
  const float* Wtail  = (const float*)d_in[20];
  const float* Whead  = (const float*)d_in[21];
  const float* Wrel   = (const float*)d_in[22];
  const float* W1     = (const float*)d_in[23];
  const float* b1     = (const float*)d_in[24];
  const float* W2     = (const float*)d_in[25];
  const float* ln1_g  = (const float*)d_in[26];
  const float* ln1_b  = (const float*)d_in[27];
  const float* Wg     = (const float*)d_in[28];
  const float* Ug     = (const float*)d_in[29];
  const float* bg     = (const float*)d_in[30];
  const float* Wr     = (const float*)d_in[31];
  const float* Ur     = (const float*)d_in[32];
  const float* br     = (const float*)d_in[33];
  float* out = (float*)d_out;

  // ---- workspace layout ----
  char* wp = (char*)d_ws;
  auto alloc = [&](size_t bytes) -> void* {
    void* p = (void*)wp;
    wp += (bytes + 255) & ~(size_t)255;
    return p;
  };
  bf16* Wrel_bf = (bf16*)alloc((size_t)512 * 65536 * 2);
  bf16* emb_bf  = (bf16*)alloc((size_t)EMB_PAD * 256 * 2);
  bf16* E4      = (bf16*)alloc((size_t)EMB_PAD * 1024 * 2);
  bf16* wcat    = (bf16*)alloc((size_t)1024 * 256 * 2);
  bf16* Vh      = (bf16*)alloc((size_t)BN * MN * 256 * 2);
  bf16* Vt      = (bf16*)alloc((size_t)BN * MN * 256 * 2);
  bf16* eRbf_g  = (bf16*)alloc((size_t)BN * 256 * 2);
  float* eLT    = (float*)alloc((size_t)256 * BN * 4);
  float* eLp     = (float*)alloc((size_t)BN * 256 * 4);
  float* eRp     = (float*)alloc((size_t)BN * 256 * 4);
  float* bil_part= (float*)alloc((size_t)SPLITK * BN * 512 * 4);
  float* qkbuf   = (float*)alloc((size_t)2 * BN * 256 * 4);
  float* ovbuf   = (float*)alloc((size_t)2 * BN * 256 * 4);
  float* enh_h   = (float*)alloc((size_t)BN * 256 * 4);
  float* enh_t   = (float*)alloc((size_t)BN * 256 * 4);
  float* pairb   = (float*)alloc((size_t)BN * 512 * 4);
  float* h1buf   = (float*)alloc((size_t)BN * 512 * 4);
  float* T_t     = (float*)alloc(256 * 256 * 4);
  float* Cq_t    = (float*)alloc(256 * 256 * 4);
  float* Wov_t   = (float*)alloc(256 * 256 * 4);
  float* Wenh_t  = (float*)alloc(256 * 256 * 4);
  float* benh_t  = (float*)alloc(256 * 4);
  float* T_e     = (float*)alloc(256 * 256 * 4);
  float* Cq_e    = (float*)alloc(256 * 256 * 4);
  float* Wov_e   = (float*)alloc(256 * 256 * 4);
  float* Wenh_e  = (float*)alloc(256 * 256 * 4);
  float* benh_e  = (float*)alloc(256 * 4);
  float* Whead_kn= (float*)alloc(256 * 256 * 4);
  float* WtailT  = (float*)alloc(256 * 256 * 4);
  float* W1_kn   = (float*)alloc(512 * 512 * 4);
  float* W2_kn   = (float*)alloc(512 * 512 * 4);

  // ---- 1: all independent precompute ----
  k_stage1<<<S1_GRID, 256, 0, stream>>>(Wbil_t, Wq_t, Wbil_e, Wq_e, Wo_t, Wv_t, Wo_e, Wv_e,
                                        Wtail, Whead, W1, W2, Wg, Ug, Wr, Ur, Wrel, emb,
                                        entity_pairs,
                                        T_t, T_e, Wov_t, Wov_e, WtailT, Whead_kn, W1_kn, W2_kn,
                                        wcat, emb_bf, eLp, eRp, eRbf_g, eLT, Wrel_bf);
  // ---- 2: bilinear right after stage1 (Wrel_bf L3-warm; owns caches) ----
  k_bilinear<<<2048, 256, 0, stream>>>(eRbf_g, eLT, Wrel_bf, bil_part);
  // ---- 3: e4 (quadrant-LDS wcat, coalesced epilogue) + stage-2 weight products ----
  k_e4s2<<<4161, 256, 0, stream>>>(emb_bf, wcat, E4,
                                   T_t, Wk_t, Cq_t, T_e, Wk_e, Cq_e,
                                   Wov_t, WtailT, Wenh_t, Wov_e, Wenh_e,
                                   Wtail, bo_t, bo_e, benh_t, benh_e);
  // ---- 4: merged qk12(first) + vbuild ----
  k_vq<<<33024, 256, 0, stream>>>(left_conn, right_conn, emb_bf, E4, bg, br, Vh, Vt,
                                  bil_part, Cq_t, qkbuf);
  // ---- stage A: chains 1+2 ----
  k_attn_dual<<<4096, 256, 0, stream>>>(qkbuf, left_conn, right_conn, Vh, Vt, 0, emb_bf, ovbuf);
  k_enh_dual<<<256, 256, 0, stream>>>(ovbuf, eLp, eRp, Wenh_t, Whead_kn, benh_t, ln_g, ln_b,
                                      enh_h, enh_t, 256, 0, 0);
  // ---- stage B: chains 3+4 ----
  k_qk34<<<256, 256, 0, stream>>>(enh_t, enh_h, Cq_e, qkbuf);
  k_attn_dual<<<4096, 256, 0, stream>>>(qkbuf, left_conn, right_conn, Vh, Vt, 1, emb_bf, ovbuf);
  k_enh_dual<<<256, 256, 0, stream>>>(ovbuf, eLp, eRp, Wenh_e, Whead_kn, benh_e, ln_g, ln_b,
                                      pairb, pairb, 512, 0, 256);

  // ---- final MLP + LN ----
  k_lin<<<dim3(128, 2), 256, 0, stream>>>(pairb, W1_kn, b1, h1buf, 512, 512, 1);
  k_mlp2ln<<<128, 256, 0, stream>>>(h1buf, W2_kn, pairb, ln1_g, ln1_b, out);
}